// Round 2
// baseline (7721.396 us; speedup 1.0000x reference)
//
#include <hip/hip_runtime.h>
#include <math.h>

#define H 200
#define PP 4
#define TT 4
#define BB 64
#define MM 1000
#define NEGV (-1e30f)

static const int ROWS = BB * MM;          // 64000
static const int UD   = 2 * H;            // 400
static const int G4H  = 4 * H;            // 800
#define KA 416                            // 400 padded to x32
#define KB 224                            // 200 padded to x32

typedef __attribute__((ext_vector_type(8))) short short8;
typedef __attribute__((ext_vector_type(4))) float f32x4;

__device__ __forceinline__ unsigned short f2bf(float x) {
  unsigned u = __float_as_uint(x);
  unsigned r = (u + 0x7fffu + ((u >> 16) & 1u)) >> 16;
  return (unsigned short)r;
}
__device__ __forceinline__ float bf2f(unsigned short h) {
  return __uint_as_float(((unsigned)h) << 16);
}
__device__ __forceinline__ void gload16(const unsigned short* g, const unsigned short* l) {
  __builtin_amdgcn_global_load_lds(
      (const __attribute__((address_space(1))) void*)g,
      (__attribute__((address_space(3))) void*)l, 16, 0, 0);
}

// ---------------------------------------------------------------- init
__global__ __launch_bounds__(256) void k_init(const int* __restrict__ dmask,
    int* st_s, int* st_e, int* ms, int* me,
    float* h, float* c, float* out) {
  int b = blockIdx.x, t = threadIdx.x;
  __shared__ int red[256];
  int sum = 0;
  for (int m = t; m < MM; m += 256) sum += dmask[b * MM + m];
  red[t] = sum; __syncthreads();
  for (int s = 128; s > 0; s >>= 1) { if (t < s) red[t] += red[t + s]; __syncthreads(); }
  if (t == 0) { st_s[b] = 0; st_e[b] = red[0] - 1; ms[b] = 1; me[b] = 1; }
  for (int i = t; i < H; i += 256) { h[b * H + i] = 0.f; c[b * H + i] = 0.f; }
  if (b == 0 && t == 0) out[0] = 0.f;
}

// ---------------------------------------------------------------- split fp32 -> bf16 hi/lo
__global__ __launch_bounds__(256) void k_split(const float* __restrict__ src, int srcld,
    int koff, int Ksrc, unsigned short* __restrict__ hi, unsigned short* __restrict__ lo,
    int Kpad) {
  int r = blockIdx.x;
  for (int k = threadIdx.x; k < Kpad; k += 256) {
    unsigned short h = 0, l = 0;
    if (k < Ksrc) {
      float x = src[(size_t)r * srcld + koff + k];
      h = f2bf(x);
      l = f2bf(x - bf2f(h));
    }
    hi[(size_t)r * Kpad + k] = h;
    lo[(size_t)r * Kpad + k] = l;
  }
}

// ---------------------------------------------------------------- LSTM
__global__ __launch_bounds__(1024) void k_lstm(
    const float* __restrict__ U, const int* __restrict__ st_s, const int* __restrict__ st_e,
    float* __restrict__ h, float* __restrict__ c,
    const float* __restrict__ w_ih, const float* __restrict__ w_hh,
    const float* __restrict__ b_ih, const float* __restrict__ b_hh,
    float* __restrict__ ucat, float* __restrict__ ue) {
  int b = blockIdx.x, t = threadIdx.x;
  __shared__ float x[800];
  __shared__ float hsh[H];
  __shared__ float g[800];
  int si = st_s[b], ei = st_e[b];
  const float* Us = U + ((size_t)b * MM + si) * UD;
  const float* Ue = U + ((size_t)b * MM + ei) * UD;
  for (int i = t; i < UD; i += 1024) { x[i] = Us[i]; x[UD + i] = Ue[i]; }
  for (int i = t; i < H; i += 1024) hsh[i] = h[b * H + i];
  __syncthreads();
  if (t < G4H) {
    float acc = b_ih[t] + b_hh[t];
    const float4* wi = (const float4*)(w_ih + (size_t)t * 800);
    for (int k = 0; k < 200; ++k) {
      float4 wv = wi[k]; const float* xv = &x[k * 4];
      acc = fmaf(wv.x, xv[0], acc); acc = fmaf(wv.y, xv[1], acc);
      acc = fmaf(wv.z, xv[2], acc); acc = fmaf(wv.w, xv[3], acc);
    }
    const float4* wh = (const float4*)(w_hh + (size_t)t * H);
    for (int k = 0; k < 50; ++k) {
      float4 wv = wh[k]; const float* hv = &hsh[k * 4];
      acc = fmaf(wv.x, hv[0], acc); acc = fmaf(wv.y, hv[1], acc);
      acc = fmaf(wv.z, hv[2], acc); acc = fmaf(wv.w, hv[3], acc);
    }
    g[t] = acc;
  }
  __syncthreads();
  if (t < H) {
    float ig = 1.f / (1.f + expf(-g[t]));
    float fg = 1.f / (1.f + expf(-g[H + t]));
    float gg = tanhf(g[2 * H + t]);
    float og = 1.f / (1.f + expf(-g[3 * H + t]));
    float cn = fg * c[b * H + t] + ig * gg;
    c[b * H + t] = cn;
    h[b * H + t] = og * tanhf(cn);
  }
  for (int i = t; i < 800; i += 1024) ucat[b * 800 + i] = x[i];
  for (int i = t; i < UD; i += 1024) ue[b * UD + i] = x[UD + i];
}

// ---------------------------------------------------------------- r + rcorr
template <int TAG>
__global__ __launch_bounds__(256) void k_r(
    const float* __restrict__ U, const int* __restrict__ st_s,
    const float* __restrict__ ucat, const float* __restrict__ ue,
    const float* __restrict__ h,
    const float* __restrict__ Wr, const float* __restrict__ W1,
    const float* __restrict__ b1, float* __restrict__ rcorr) {
  int b = blockIdx.x, t = threadIdx.x;
  __shared__ float xc[1000];
  __shared__ float r[H];
  for (int i = t; i < H; i += 256) xc[i] = h[b * H + i];
  if (TAG == 0) {
    for (int i = t; i < 800; i += 256) xc[H + i] = ucat[b * 800 + i];
  } else {
    const float* Us = U + ((size_t)b * MM + st_s[b]) * UD;
    for (int i = t; i < UD; i += 256) { xc[H + i] = Us[i]; xc[H + UD + i] = ue[b * UD + i]; }
  }
  __syncthreads();
  if (t < H) {
    float acc = 0.f;
    const float4* wr = (const float4*)(Wr + (size_t)t * 1000);
    for (int k = 0; k < 250; ++k) {
      float4 wv = wr[k]; const float* xv = &xc[k * 4];
      acc = fmaf(wv.x, xv[0], acc); acc = fmaf(wv.y, xv[1], acc);
      acc = fmaf(wv.z, xv[2], acc); acc = fmaf(wv.w, xv[3], acc);
    }
    r[t] = tanhf(acc);
  }
  __syncthreads();
  for (int j = t; j < 800; j += 256) {
    float acc = b1[j];
    const float4* w1 = (const float4*)(W1 + (size_t)j * 600 + 400);
    for (int k = 0; k < 50; ++k) {
      float4 wv = w1[k]; const float* rv = &r[k * 4];
      acc = fmaf(wv.x, rv[0], acc); acc = fmaf(wv.y, rv[1], acc);
      acc = fmaf(wv.z, rv[2], acc); acc = fmaf(wv.w, rv[3], acc);
    }
    rcorr[b * 800 + j] = acc;
  }
}

// ---------------------------------------------------------------- m1 split (new path)
__global__ __launch_bounds__(256) void k_m1s(const float* __restrict__ uw1,
    const float* __restrict__ rcorr, unsigned short* __restrict__ m1h,
    unsigned short* __restrict__ m1l) {
  int row = blockIdx.x, t = threadIdx.x;
  if (t >= KB) return;
  if (t < H) {
    int b = row / MM;
    float4 u = *(const float4*)(uw1 + (size_t)row * 800 + t * 4);
    float4 rc = *(const float4*)(rcorr + b * 800 + t * 4);
    float v = fmaxf(fmaxf(u.x + rc.x, u.y + rc.y), fmaxf(u.z + rc.z, u.w + rc.w));
    unsigned short hh = f2bf(v);
    m1h[(size_t)row * KB + t] = hh;
    m1l[(size_t)row * KB + t] = f2bf(v - bf2f(hh));
  } else {
    m1h[(size_t)row * KB + t] = 0;
    m1l[(size_t)row * KB + t] = 0;
  }
}

// ---------------------------------------------------------------- MFMA split-bf16 GEMM
// C = A @ B^T (A: M x Ka bf16-pair, B: N x Ka bf16-pair), 3-pass hi/lo.
// MODE 0: store fp32 C[M][Nld] (cols < N). MODE 1: +bias, maxpool4 cols -> C[M][Nld].
template <int MODE>
__global__ __launch_bounds__(256) void k_mgemm(
    const unsigned short* __restrict__ Ah, const unsigned short* __restrict__ Al,
    const unsigned short* __restrict__ Bh, const unsigned short* __restrict__ Bl,
    int Ka, const float* __restrict__ bias,
    float* __restrict__ C, int N, int Nld) {
  __shared__ unsigned short lds[16384];   // Ah | Al | Bh | Bl : 4096 ushorts each
  const int tid = threadIdx.x;
  const int lane = tid & 63, wave = tid >> 6;
  const int wm = wave >> 1, wn = wave & 1;
  const int row0 = blockIdx.x * 128, n0 = blockIdx.y * 128;
  const int lr = lane & 15, ls = lane >> 4;

  f32x4 acc[4][4];
#pragma unroll
  for (int i = 0; i < 4; ++i)
#pragma unroll
    for (int j = 0; j < 4; ++j) acc[i][j] = (f32x4){0.f, 0.f, 0.f, 0.f};

  const int nk = Ka >> 5;
  for (int kt = 0; kt < nk; ++kt) {
    const int k0 = kt << 5;
#pragma unroll
    for (int i = 0; i < 2; ++i) {
      const int cb = i * 256 + wave * 64;          // wave-uniform chunk base
      const int c = cb + lane;
      const int rr = c >> 2, sl = c & 3;
      const size_t ga = (size_t)(row0 + rr) * Ka + k0 + sl * 8;
      int rb = n0 + rr; rb = rb < N ? rb : N - 1;
      const size_t gb = (size_t)rb * Ka + k0 + sl * 8;
      const unsigned short* ldsb = lds + cb * 8;   // cb*16 bytes
      gload16(Ah + ga, ldsb);
      gload16(Al + ga, ldsb + 4096);
      gload16(Bh + gb, ldsb + 8192);
      gload16(Bl + gb, ldsb + 12288);
    }
    __syncthreads();
    short8 ah[4], al[4], bh[4], bl[4];
    const int aoff = (wm * 64 + lr) * 32 + ls * 8;
    const int boff = (wn * 64 + lr) * 32 + ls * 8;
#pragma unroll
    for (int i = 0; i < 4; ++i) {
      ah[i] = *(const short8*)(lds + aoff + i * 512);
      al[i] = *(const short8*)(lds + 4096 + aoff + i * 512);
      bh[i] = *(const short8*)(lds + 8192 + boff + i * 512);
      bl[i] = *(const short8*)(lds + 12288 + boff + i * 512);
    }
#pragma unroll
    for (int i = 0; i < 4; ++i)
#pragma unroll
      for (int j = 0; j < 4; ++j)
        acc[i][j] = __builtin_amdgcn_mfma_f32_16x16x32_bf16(ah[i], bh[j], acc[i][j], 0, 0, 0);
#pragma unroll
    for (int i = 0; i < 4; ++i)
#pragma unroll
      for (int j = 0; j < 4; ++j)
        acc[i][j] = __builtin_amdgcn_mfma_f32_16x16x32_bf16(ah[i], bl[j], acc[i][j], 0, 0, 0);
#pragma unroll
    for (int i = 0; i < 4; ++i)
#pragma unroll
      for (int j = 0; j < 4; ++j)
        acc[i][j] = __builtin_amdgcn_mfma_f32_16x16x32_bf16(al[i], bh[j], acc[i][j], 0, 0, 0);
    __syncthreads();
  }

  const int colb = n0 + wn * 64 + lr;
  const int rowb = row0 + wm * 64 + ls * 4;
  if (MODE == 0) {
#pragma unroll
    for (int i = 0; i < 4; ++i) {
#pragma unroll
      for (int j = 0; j < 4; ++j) {
        const int col = colb + j * 16;
        if (col < N) {
          const int rb2 = rowb + i * 16;
#pragma unroll
          for (int r = 0; r < 4; ++r)
            C[(size_t)(rb2 + r) * Nld + col] = acc[i][j][r];
        }
      }
    }
  } else {
#pragma unroll
    for (int j = 0; j < 4; ++j) {
      const int col = colb + j * 16;
      const float bv = (col < N) ? bias[col] : 0.f;
#pragma unroll
      for (int i = 0; i < 4; ++i) {
        const int rb2 = rowb + i * 16;
#pragma unroll
        for (int r = 0; r < 4; ++r) {
          float v = acc[i][j][r] + bv;
          v = fmaxf(v, __shfl_xor(v, 1));
          v = fmaxf(v, __shfl_xor(v, 2));
          if ((lane & 3) == 0 && col < N)
            C[(size_t)(rb2 + r) * Nld + (col >> 2)] = v;
        }
      }
    }
  }
}

// ---------------------------------------------------------------- alpha (new path: m1 pair)
__global__ __launch_bounds__(256) void k_alpha2(const unsigned short* __restrict__ m1h,
    const unsigned short* __restrict__ m1l, const float* __restrict__ m2,
    const float* __restrict__ W12, const float* __restrict__ b12,
    float* __restrict__ alpha) {
  int wid = threadIdx.x >> 6, lane = threadIdx.x & 63;
  size_t row = (size_t)blockIdx.x * 4 + wid;
  const unsigned short* r1h = m1h + row * KB;
  const unsigned short* r1l = m1l + row * KB;
  const float* r2 = m2 + row * H;
  float a0 = 0.f, a1 = 0.f, a2 = 0.f, a3 = 0.f;
  for (int k = lane; k < H; k += 64) {
    float v1 = bf2f(r1h[k]) + bf2f(r1l[k]);
    float v2 = r2[k];
    a0 += v1 * W12[0 * 400 + k] + v2 * W12[0 * 400 + 200 + k];
    a1 += v1 * W12[1 * 400 + k] + v2 * W12[1 * 400 + 200 + k];
    a2 += v1 * W12[2 * 400 + k] + v2 * W12[2 * 400 + 200 + k];
    a3 += v1 * W12[3 * 400 + k] + v2 * W12[3 * 400 + 200 + k];
  }
  for (int off = 32; off > 0; off >>= 1) {
    a0 += __shfl_down(a0, off); a1 += __shfl_down(a1, off);
    a2 += __shfl_down(a2, off); a3 += __shfl_down(a3, off);
  }
  if (lane == 0) {
    float m = fmaxf(fmaxf(a0 + b12[0], a1 + b12[1]), fmaxf(a2 + b12[2], a3 + b12[3]));
    alpha[row] = m;
  }
}

// ================= OLD fp32 fallback kernels (round-1, proven) =================
__global__ __launch_bounds__(256) void k_m1(const float* __restrict__ uw1,
    const float* __restrict__ rcorr, float* __restrict__ m1) {
  int row = blockIdx.x, t = threadIdx.x;
  if (t >= H) return;
  int b = row / MM;
  float4 u = *(const float4*)(uw1 + (size_t)row * 800 + t * 4);
  float4 rc = *(const float4*)(rcorr + b * 800 + t * 4);
  float v = fmaxf(fmaxf(u.x + rc.x, u.y + rc.y), fmaxf(u.z + rc.z, u.w + rc.w));
  m1[(size_t)row * H + t] = v;
}

template <int MODE>
__global__ __launch_bounds__(256) void k_gemm(
    const float* __restrict__ A, int lda,
    const float* __restrict__ B, int ldb,
    const float* __restrict__ bias,
    const float* __restrict__ addend,
    float* __restrict__ C, int N, int K) {
  __shared__ float As[2][8][128];
  __shared__ float Bs[2][8][128];
  const int tid = threadIdx.x;
  const int tx = tid & 15, ty = tid >> 4;
  const int row0 = blockIdx.x * 128, n0 = blockIdx.y * 128;
  float acc[8][8];
#pragma unroll
  for (int i = 0; i < 8; ++i)
#pragma unroll
    for (int j = 0; j < 8; ++j) acc[i][j] = 0.f;
  const int lr = tid >> 1;
  const int lk = (tid & 1) * 4;
  const float* Ap = A + (size_t)(row0 + lr) * lda + lk;
  const int bcol = n0 + lr;
  const float* Bp = B + (size_t)bcol * ldb + lk;
  const bool bok = bcol < N;
  const int nk = K >> 3;
  float4 av = *(const float4*)Ap;
  float4 bv = bok ? *(const float4*)Bp : make_float4(0.f, 0.f, 0.f, 0.f);
  As[0][lk + 0][lr] = av.x; As[0][lk + 1][lr] = av.y;
  As[0][lk + 2][lr] = av.z; As[0][lk + 3][lr] = av.w;
  Bs[0][lk + 0][lr] = bv.x; Bs[0][lk + 1][lr] = bv.y;
  Bs[0][lk + 2][lr] = bv.z; Bs[0][lk + 3][lr] = bv.w;
  __syncthreads();
  for (int kt = 0; kt < nk; ++kt) {
    const int buf = kt & 1;
    if (kt + 1 < nk) {
      av = *(const float4*)(Ap + (kt + 1) * 8);
      bv = bok ? *(const float4*)(Bp + (kt + 1) * 8) : make_float4(0.f, 0.f, 0.f, 0.f);
    }
#pragma unroll
    for (int k = 0; k < 8; ++k) {
      float a[8], b[8];
      *(float4*)&a[0] = *(const float4*)&As[buf][k][ty * 4];
      *(float4*)&a[4] = *(const float4*)&As[buf][k][64 + ty * 4];
      *(float4*)&b[0] = *(const float4*)&Bs[buf][k][tx * 4];
      *(float4*)&b[4] = *(const float4*)&Bs[buf][k][64 + tx * 4];
#pragma unroll
      for (int i = 0; i < 8; ++i)
#pragma unroll
        for (int j = 0; j < 8; ++j) acc[i][j] = fmaf(a[i], b[j], acc[i][j]);
    }
    if (kt + 1 < nk) {
      const int nb = buf ^ 1;
      As[nb][lk + 0][lr] = av.x; As[nb][lk + 1][lr] = av.y;
      As[nb][lk + 2][lr] = av.z; As[nb][lk + 3][lr] = av.w;
      Bs[nb][lk + 0][lr] = bv.x; Bs[nb][lk + 1][lr] = bv.y;
      Bs[nb][lk + 2][lr] = bv.z; Bs[nb][lk + 3][lr] = bv.w;
    }
    __syncthreads();
  }
#pragma unroll
  for (int ih = 0; ih < 2; ++ih) {
#pragma unroll
    for (int i = 0; i < 4; ++i) {
      const int row = row0 + ih * 64 + ty * 4 + i;
      const int ai = ih * 4 + i;
      if (MODE == 0) {
#pragma unroll
        for (int jh = 0; jh < 2; ++jh) {
          const int col = n0 + jh * 64 + tx * 4;
          if (col < N) {
            float4 v = make_float4(acc[ai][jh * 4 + 0], acc[ai][jh * 4 + 1],
                                   acc[ai][jh * 4 + 2], acc[ai][jh * 4 + 3]);
            *(float4*)(C + (size_t)row * N + col) = v;
          }
        }
      } else {
        const int bidx = row / MM;
#pragma unroll
        for (int jh = 0; jh < 2; ++jh) {
          const int col = n0 + jh * 64 + tx * 4;
          if (col < N) {
            float m = -3.4e38f;
#pragma unroll
            for (int j = 0; j < 4; ++j) {
              float v = acc[ai][jh * 4 + j];
              if (MODE == 2) v += bias[col + j];
              if (MODE == 1) v += addend[bidx * 800 + col + j];
              m = fmaxf(m, v);
            }
            C[(size_t)row * (N >> 2) + (col >> 2)] = m;
          }
        }
      }
    }
  }
}

__global__ __launch_bounds__(256) void k_alpha(const float* __restrict__ m1,
    const float* __restrict__ m2, const float* __restrict__ W12,
    const float* __restrict__ b12, float* __restrict__ alpha) {
  int wid = threadIdx.x >> 6, lane = threadIdx.x & 63;
  size_t row = (size_t)blockIdx.x * 4 + wid;
  const float* r1 = m1 + row * H;
  const float* r2 = m2 + row * H;
  float a0 = 0.f, a1 = 0.f, a2 = 0.f, a3 = 0.f;
  for (int k = lane; k < H; k += 64) {
    float v1 = r1[k], v2 = r2[k];
    a0 += v1 * W12[0 * 400 + k] + v2 * W12[0 * 400 + 200 + k];
    a1 += v1 * W12[1 * 400 + k] + v2 * W12[1 * 400 + 200 + k];
    a2 += v1 * W12[2 * 400 + k] + v2 * W12[2 * 400 + 200 + k];
    a3 += v1 * W12[3 * 400 + k] + v2 * W12[3 * 400 + 200 + k];
  }
  for (int off = 32; off > 0; off >>= 1) {
    a0 += __shfl_down(a0, off); a1 += __shfl_down(a1, off);
    a2 += __shfl_down(a2, off); a3 += __shfl_down(a3, off);
  }
  if (lane == 0) {
    float m = fmaxf(fmaxf(a0 + b12[0], a1 + b12[1]), fmaxf(a2 + b12[2], a3 + b12[3]));
    alpha[row] = m;
  }
}

// ---------------------------------------------------------------- argmax + logsumexp
__global__ __launch_bounds__(256) void k_reduce(const float* __restrict__ alpha,
    const int* __restrict__ dmask, const int* __restrict__ span, int tag,
    int* __restrict__ idx_out, float* __restrict__ atgt_out) {
  int b = blockIdx.x, t = threadIdx.x;
  __shared__ float vals[MM];
  __shared__ float rv[256];
  __shared__ int ri[256];
  float bestv = -3.4e38f; int besti = 0x7fffffff;
  for (int m = t; m < MM; m += 256) {
    float v = alpha[b * MM + m];
    if (!dmask[b * MM + m]) v += NEGV;
    vals[m] = v;
    if (v > bestv || (v == bestv && m < besti)) { bestv = v; besti = m; }
  }
  rv[t] = bestv; ri[t] = besti; __syncthreads();
  for (int s = 128; s > 0; s >>= 1) {
    if (t < s) {
      float v2 = rv[t + s]; int i2 = ri[t + s];
      if (v2 > rv[t] || (v2 == rv[t] && i2 < ri[t])) { rv[t] = v2; ri[t] = i2; }
    }
    __syncthreads();
  }
  float vmax = rv[0]; int vidx = ri[0];
  __syncthreads();
  float se = 0.f;
  for (int m = t; m < MM; m += 256) se += expf(vals[m] - vmax);
  rv[t] = se; __syncthreads();
  for (int s = 128; s > 0; s >>= 1) { if (t < s) rv[t] += rv[t + s]; __syncthreads(); }
  if (t == 0) {
    int tgt = span[b * 2 + tag];
    atgt_out[b] = vals[tgt] - vmax - logf(rv[0]);
    idx_out[b] = vidx;
  }
}

// ---------------------------------------------------------------- state update + loss
__global__ __launch_bounds__(64) void k_update(const int* __restrict__ idx_buf,
    const float* __restrict__ atgt, int* __restrict__ st, int* __restrict__ mstate,
    float* __restrict__ pout, float* __restrict__ loss, int first) {
  int b = threadIdx.x;
  int idx = idx_buf[b];
  int sold = st[b], msold = mstate[b];
  int snew = first ? idx : (msold ? idx : 0);
  int msnew = first ? 1 : ((snew != (msold ? sold : 0)) ? 1 : 0);
  st[b] = snew; mstate[b] = msnew;
  if (msnew) pout[b] = (float)snew;
  float asum = atgt[b];
  float csum = (float)msnew;
  for (int off = 32; off > 0; off >>= 1) {
    asum += __shfl_down(asum, off);
    csum += __shfl_down(csum, off);
  }
  if (b == 0) loss[0] += (-asum / (float)BB) * csum / (float)(BB * TT);
}

// ---------------------------------------------------------------- launch
extern "C" void kernel_launch(void* const* d_in, const int* in_sizes, int n_in,
                              void* d_out, int out_size, void* d_ws, size_t ws_size,
                              hipStream_t stream) {
  const float* U     = (const float*)d_in[0];
  const int*   dmask = (const int*)d_in[1];
  const int*   span  = (const int*)d_in[2];
  const float* w_ih  = (const float*)d_in[3];
  const float* w_hh  = (const float*)d_in[4];
  const float* b_ih  = (const float*)d_in[5];
  const float* b_hh  = (const float*)d_in[6];
  const float* Wr[2]  = {(const float*)d_in[7],  (const float*)d_in[14]};
  const float* W1[2]  = {(const float*)d_in[8],  (const float*)d_in[15]};
  const float* b1[2]  = {(const float*)d_in[9],  (const float*)d_in[16]};
  const float* W2[2]  = {(const float*)d_in[10], (const float*)d_in[17]};
  const float* b2[2]  = {(const float*)d_in[11], (const float*)d_in[18]};
  const float* W12[2] = {(const float*)d_in[12], (const float*)d_in[19]};
  const float* b12[2] = {(const float*)d_in[13], (const float*)d_in[20]};
  float* out = (float*)d_out;

  size_t off = 0;
  char* base = (char*)d_ws;
  auto alloc = [&](size_t n) {
    void* p = base + off;
    off += (n + 255) & ~(size_t)255;
    return p;
  };
  // small shared buffers (both paths)
  float* alph  = (float*)alloc((size_t)BB * MM * 4);
  float* rcorr = (float*)alloc((size_t)BB * 800 * 4);
  float* ucat  = (float*)alloc((size_t)BB * 800 * 4);
  float* ue    = (float*)alloc((size_t)BB * UD * 4);
  float* hbuf  = (float*)alloc((size_t)BB * H * 4);
  float* cbuf  = (float*)alloc((size_t)BB * H * 4);
  float* atgt  = (float*)alloc((size_t)BB * 4);
  int* st_s = (int*)alloc(BB * 4);
  int* st_e = (int*)alloc(BB * 4);
  int* msb  = (int*)alloc(BB * 4);
  int* meb  = (int*)alloc(BB * 4);
  int* idxb = (int*)alloc(BB * 4);

  const size_t UH_B = (size_t)ROWS * KA * 2;       // 53,248,000
  const size_t M1_B = (size_t)ROWS * KB * 2;       // 28,672,000
  const size_t M2_B = (size_t)ROWS * H * 4;        // 51,200,000
  const size_t REGION = 2 * M1_B + M2_B;           // 108,544,000 > 2*UH_B
  const size_t UW1_B = (size_t)ROWS * 800 * 4;     // 204,800,000
  const size_t W1S_B = (size_t)800 * KA * 2;
  const size_t W2S_B = (size_t)800 * KB * 2;
  size_t new_need = off + REGION + 2 * UW1_B + 4 * W1S_B + 4 * W2S_B + 4096;

  if (ws_size >= new_need) {
    // ---------------- NEW: MFMA split-bf16 path ----------------
    char* region = (char*)alloc(REGION);
    unsigned short* Uh = (unsigned short*)region;
    unsigned short* Ul = (unsigned short*)(region + UH_B);
    unsigned short* m1h = (unsigned short*)region;               // aliases Uh/Ul (disjoint lifetime)
    unsigned short* m1l = (unsigned short*)(region + M1_B);
    float* m2 = (float*)(region + 2 * M1_B);
    float* uw1[2];
    uw1[0] = (float*)alloc(UW1_B);
    uw1[1] = (float*)alloc(UW1_B);
    unsigned short *W1h[2], *W1l[2], *W2h[2], *W2l[2];
    for (int g = 0; g < 2; ++g) {
      W1h[g] = (unsigned short*)alloc(W1S_B);
      W1l[g] = (unsigned short*)alloc(W1S_B);
      W2h[g] = (unsigned short*)alloc(W2S_B);
      W2l[g] = (unsigned short*)alloc(W2S_B);
    }

    k_init<<<BB, 256, 0, stream>>>(dmask, st_s, st_e, msb, meb, hbuf, cbuf, out);
    k_split<<<ROWS, 256, 0, stream>>>(U, UD, 0, UD, Uh, Ul, KA);
    for (int g = 0; g < 2; ++g) {
      k_split<<<800, 256, 0, stream>>>(W1[g], 600, 0, 400, W1h[g], W1l[g], KA);
      k_split<<<800, 256, 0, stream>>>(W2[g], 200, 0, 200, W2h[g], W2l[g], KB);
    }
    dim3 gg(ROWS / 128, 7);
    k_mgemm<0><<<gg, 256, 0, stream>>>(Uh, Ul, W1h[0], W1l[0], KA, nullptr, uw1[0], 800, 800);
    k_mgemm<0><<<gg, 256, 0, stream>>>(Uh, Ul, W1h[1], W1l[1], KA, nullptr, uw1[1], 800, 800);

    for (int t = 0; t < TT; ++t) {
      int first = (t == 0) ? 1 : 0;
      k_lstm<<<BB, 1024, 0, stream>>>(U, st_s, st_e, hbuf, cbuf, w_ih, w_hh, b_ih, b_hh, ucat, ue);

      k_r<0><<<BB, 256, 0, stream>>>(U, st_s, ucat, ue, hbuf, Wr[0], W1[0], b1[0], rcorr);
      k_m1s<<<ROWS, 256, 0, stream>>>(uw1[0], rcorr, m1h, m1l);
      k_mgemm<1><<<gg, 256, 0, stream>>>(m1h, m1l, W2h[0], W2l[0], KB, b2[0], m2, 800, 200);
      k_alpha2<<<ROWS / 4, 256, 0, stream>>>(m1h, m1l, m2, W12[0], b12[0], alph);
      k_reduce<<<BB, 256, 0, stream>>>(alph, dmask, span, 0, idxb, atgt);
      k_update<<<1, 64, 0, stream>>>(idxb, atgt, st_s, msb, out + 1, out, first);

      k_r<1><<<BB, 256, 0, stream>>>(U, st_s, ucat, ue, hbuf, Wr[1], W1[1], b1[1], rcorr);
      k_m1s<<<ROWS, 256, 0, stream>>>(uw1[1], rcorr, m1h, m1l);
      k_mgemm<1><<<gg, 256, 0, stream>>>(m1h, m1l, W2h[1], W2l[1], KB, b2[1], m2, 800, 200);
      k_alpha2<<<ROWS / 4, 256, 0, stream>>>(m1h, m1l, m2, W12[1], b12[1], alph);
      k_reduce<<<BB, 256, 0, stream>>>(alph, dmask, span, 1, idxb, atgt);
      k_update<<<1, 64, 0, stream>>>(idxb, atgt, st_e, meb, out + 1 + BB, out, first);
    }
  } else {
    // ---------------- OLD: fp32 fallback path (round-1) ----------------
    float* m1 = (float*)alloc((size_t)ROWS * H * 4);
    float* m2 = (float*)alloc((size_t)ROWS * H * 4);
    size_t base_used = off;
    bool precomp = (ws_size > base_used) &&
                   ((ws_size - base_used) >= 2 * (size_t)ROWS * 800 * 4 + 1024);
    float* uw1[2] = {nullptr, nullptr};
    if (precomp) {
      uw1[0] = (float*)alloc((size_t)ROWS * 800 * 4);
      uw1[1] = (float*)alloc((size_t)ROWS * 800 * 4);
    }
    dim3 gg(ROWS / 128, (800 + 127) / 128);
    k_init<<<BB, 256, 0, stream>>>(dmask, st_s, st_e, msb, meb, hbuf, cbuf, out);
    if (precomp) {
      k_gemm<0><<<gg, 256, 0, stream>>>(U, UD, W1[0], 600, nullptr, nullptr, uw1[0], 800, 400);
      k_gemm<0><<<gg, 256, 0, stream>>>(U, UD, W1[1], 600, nullptr, nullptr, uw1[1], 800, 400);
    }
    for (int t = 0; t < TT; ++t) {
      int first = (t == 0) ? 1 : 0;
      k_lstm<<<BB, 1024, 0, stream>>>(U, st_s, st_e, hbuf, cbuf, w_ih, w_hh, b_ih, b_hh, ucat, ue);
      k_r<0><<<BB, 256, 0, stream>>>(U, st_s, ucat, ue, hbuf, Wr[0], W1[0], b1[0], rcorr);
      if (precomp)
        k_m1<<<ROWS, 256, 0, stream>>>(uw1[0], rcorr, m1);
      else
        k_gemm<1><<<gg, 256, 0, stream>>>(U, UD, W1[0], 600, nullptr, rcorr, m1, 800, 400);
      k_gemm<2><<<gg, 256, 0, stream>>>(m1, H, W2[0], H, b2[0], nullptr, m2, 800, 200);
      k_alpha<<<ROWS / 4, 256, 0, stream>>>(m1, m2, W12[0], b12[0], alph);
      k_reduce<<<BB, 256, 0, stream>>>(alph, dmask, span, 0, idxb, atgt);
      k_update<<<1, 64, 0, stream>>>(idxb, atgt, st_s, msb, out + 1, out, first);
      k_r<1><<<BB, 256, 0, stream>>>(U, st_s, ucat, ue, hbuf, Wr[1], W1[1], b1[1], rcorr);
      if (precomp)
        k_m1<<<ROWS, 256, 0, stream>>>(uw1[1], rcorr, m1);
      else
        k_gemm<1><<<gg, 256, 0, stream>>>(U, UD, W1[1], 600, nullptr, rcorr, m1, 800, 400);
      k_gemm<2><<<gg, 256, 0, stream>>>(m1, H, W2[1], H, b2[1], nullptr, m2, 800, 200);
      k_alpha<<<ROWS / 4, 256, 0, stream>>>(m1, m2, W12[1], b12[1], alph);
      k_reduce<<<BB, 256, 0, stream>>>(alph, dmask, span, 1, idxb, atgt);
      k_update<<<1, 64, 0, stream>>>(idxb, atgt, st_e, meb, out + 1 + BB, out, first);
    }
  }
}

// Round 3
// 3217.426 us; speedup vs baseline: 2.3999x; 2.3999x over previous
//
#include <hip/hip_runtime.h>
#include <math.h>

#define H 200
#define TT 4
#define BB 64
#define MM 1000
#define NEGV (-1e30f)

static const int ROWS = BB * MM;   // 64000
#define KA 416                     // 400 padded
#define KB 224                     // 200 padded
#define NPAD 896                   // 800 padded to 7*128
#define NSLICE 28                  // 14 per GEMM family

typedef __attribute__((ext_vector_type(8))) short short8;
typedef __attribute__((ext_vector_type(4))) float f32x4;

// truncation hi/lo split: (hi+lo) rel err ~2^-16
__device__ __forceinline__ void split2(float x, unsigned short& h, unsigned short& l) {
  unsigned u = __float_as_uint(x);
  h = (unsigned short)(u >> 16);
  float res = x - __uint_as_float(u & 0xffff0000u);
  l = (unsigned short)(__float_as_uint(res) >> 16);
}

// ---------------------------------------------------------------- init
__global__ __launch_bounds__(256) void k_init(const int* __restrict__ dmask,
    int* st_s, int* st_e, int* ms, int* me,
    float* h, float* c, float* out) {
  int b = blockIdx.x, t = threadIdx.x;
  __shared__ int red[256];
  int sum = 0;
  for (int m = t; m < MM; m += 256) sum += dmask[b * MM + m];
  red[t] = sum; __syncthreads();
  for (int s = 128; s > 0; s >>= 1) { if (t < s) red[t] += red[t + s]; __syncthreads(); }
  if (t == 0) { st_s[b] = 0; st_e[b] = red[0] - 1; ms[b] = 1; me[b] = 1; }
  for (int i = t; i < H; i += 256) { h[b * H + i] = 0.f; c[b * H + i] = 0.f; }
  if (b == 0 && t == 0) out[0] = 0.f;
}

// ---------------------------------------------------------------- weight split (once)
// rows >= Nsrc or cols >= Ksrc are zeroed. grid = NPAD blocks.
__global__ __launch_bounds__(256) void k_split(const float* __restrict__ src, int srcld,
    int koff, int Ksrc, int Nsrc,
    unsigned short* __restrict__ hi, unsigned short* __restrict__ lo, int Kpad) {
  int r = blockIdx.x;
  for (int k = threadIdx.x; k < Kpad; k += 256) {
    unsigned short h = 0, l = 0;
    if (r < Nsrc && k < Ksrc) split2(src[(size_t)r * srcld + koff + k], h, l);
    hi[(size_t)r * Kpad + k] = h;
    lo[(size_t)r * Kpad + k] = l;
  }
}

// ---------------------------------------------------------------- LSTM + r(tag s) + rcorr
__global__ __launch_bounds__(1024) void k_lstm_r(
    const float* __restrict__ U, const int* __restrict__ st_s, const int* __restrict__ st_e,
    float* __restrict__ h, float* __restrict__ c,
    const float* __restrict__ w_ih, const float* __restrict__ w_hh,
    const float* __restrict__ b_ih, const float* __restrict__ b_hh,
    const float* __restrict__ Wr, const float* __restrict__ W1, const float* __restrict__ b1,
    float* __restrict__ rcorr, float* __restrict__ ue) {
  int b = blockIdx.x, t = threadIdx.x;
  __shared__ float xc[1000];   // [h_new(200) | u_cat(800)]
  __shared__ float hold[H];
  __shared__ float g[800];
  __shared__ float r[H];
  int si = st_s[b], ei = st_e[b];
  const float* Us = U + ((size_t)b * MM + si) * 400;
  const float* Ue = U + ((size_t)b * MM + ei) * 400;
  if (t < 400) { xc[200 + t] = Us[t]; xc[600 + t] = Ue[t]; ue[b * 400 + t] = Ue[t]; }
  if (t >= 400 && t < 600) hold[t - 400] = h[b * H + (t - 400)];
  __syncthreads();
  if (t < 800) {
    float acc = b_ih[t] + b_hh[t];
    const float4* wi = (const float4*)(w_ih + (size_t)t * 800);
    const float* xv = &xc[200];
    for (int k = 0; k < 200; ++k) {
      float4 wv = wi[k];
      acc = fmaf(wv.x, xv[k * 4 + 0], acc); acc = fmaf(wv.y, xv[k * 4 + 1], acc);
      acc = fmaf(wv.z, xv[k * 4 + 2], acc); acc = fmaf(wv.w, xv[k * 4 + 3], acc);
    }
    const float4* wh = (const float4*)(w_hh + (size_t)t * H);
    for (int k = 0; k < 50; ++k) {
      float4 wv = wh[k];
      acc = fmaf(wv.x, hold[k * 4 + 0], acc); acc = fmaf(wv.y, hold[k * 4 + 1], acc);
      acc = fmaf(wv.z, hold[k * 4 + 2], acc); acc = fmaf(wv.w, hold[k * 4 + 3], acc);
    }
    g[t] = acc;
  }
  __syncthreads();
  if (t < H) {
    float ig = 1.f / (1.f + expf(-g[t]));
    float fg = 1.f / (1.f + expf(-g[H + t]));
    float gg = tanhf(g[2 * H + t]);
    float og = 1.f / (1.f + expf(-g[3 * H + t]));
    float cn = fg * c[b * H + t] + ig * gg;
    c[b * H + t] = cn;
    float hv = og * tanhf(cn);
    h[b * H + t] = hv;
    xc[t] = hv;
  }
  __syncthreads();
  if (t < H) {
    float acc = 0.f;
    const float4* wr = (const float4*)(Wr + (size_t)t * 1000);
    for (int k = 0; k < 250; ++k) {
      float4 wv = wr[k];
      acc = fmaf(wv.x, xc[k * 4 + 0], acc); acc = fmaf(wv.y, xc[k * 4 + 1], acc);
      acc = fmaf(wv.z, xc[k * 4 + 2], acc); acc = fmaf(wv.w, xc[k * 4 + 3], acc);
    }
    r[t] = tanhf(acc);
  }
  __syncthreads();
  if (t < NPAD) {
    float acc = 0.f;
    if (t < 800) {
      acc = b1[t];
      const float4* w1 = (const float4*)(W1 + (size_t)t * 600 + 400);
      for (int k = 0; k < 50; ++k) {
        float4 wv = w1[k];
        acc = fmaf(wv.x, r[k * 4 + 0], acc); acc = fmaf(wv.y, r[k * 4 + 1], acc);
        acc = fmaf(wv.z, r[k * 4 + 2], acc); acc = fmaf(wv.w, r[k * 4 + 3], acc);
      }
    }
    rcorr[b * NPAD + t] = acc;
  }
}

// ---------------------------------------------------------------- r(tag e) + rcorr
__global__ __launch_bounds__(1024) void k_re(
    const float* __restrict__ U, const int* __restrict__ st_s,
    const float* __restrict__ ue, const float* __restrict__ h,
    const float* __restrict__ Wr, const float* __restrict__ W1, const float* __restrict__ b1,
    float* __restrict__ rcorr) {
  int b = blockIdx.x, t = threadIdx.x;
  __shared__ float xc[1000];
  __shared__ float r[H];
  const float* Us = U + ((size_t)b * MM + st_s[b]) * 400;
  if (t < 200) xc[t] = h[b * H + t];
  if (t >= 200 && t < 600) xc[t] = Us[t - 200];
  if (t >= 600 && t < 1000) xc[t] = ue[b * 400 + (t - 600)];
  __syncthreads();
  if (t < H) {
    float acc = 0.f;
    const float4* wr = (const float4*)(Wr + (size_t)t * 1000);
    for (int k = 0; k < 250; ++k) {
      float4 wv = wr[k];
      acc = fmaf(wv.x, xc[k * 4 + 0], acc); acc = fmaf(wv.y, xc[k * 4 + 1], acc);
      acc = fmaf(wv.z, xc[k * 4 + 2], acc); acc = fmaf(wv.w, xc[k * 4 + 3], acc);
    }
    r[t] = tanhf(acc);
  }
  __syncthreads();
  if (t < NPAD) {
    float acc = 0.f;
    if (t < 800) {
      acc = b1[t];
      const float4* w1 = (const float4*)(W1 + (size_t)t * 600 + 400);
      for (int k = 0; k < 50; ++k) {
        float4 wv = w1[k];
        acc = fmaf(wv.x, r[k * 4 + 0], acc); acc = fmaf(wv.y, r[k * 4 + 1], acc);
        acc = fmaf(wv.z, r[k * 4 + 2], acc); acc = fmaf(wv.w, r[k * 4 + 3], acc);
      }
    }
    rcorr[b * NPAD + t] = acc;
  }
}

// ---------------------------------------------------------------- MFMA GEMM, fp32 A split
// in-register, 3-pass hi/lo, fused epilogue (add + maxpool4 + alpha partials).
// MODE 0 (m1): A=U (lda=400,Ksrc=400,Kpad=416), add rcorr[b][col], write m1[row][224],
//              partial slices 0..13 with W12[p][h].
// MODE 1 (m2): A=m1 (lda=224,Ksrc=224,Kpad=224), add b2[col], no C write,
//              partial slices 14..27 with W12[p][200+h].
template <int MODE>
__global__ __launch_bounds__(256) void k_mgemm(
    const float* __restrict__ A, int lda, int KsrcA,
    const unsigned short* __restrict__ Bh, const unsigned short* __restrict__ Bl, int Kpad,
    const float* __restrict__ addv, float* __restrict__ Cout,
    float* __restrict__ partial, const float* __restrict__ W12, int slice_base) {
  __shared__ unsigned short sAh[4096], sAl[4096], sBh[4096], sBl[4096];
  const int tid = threadIdx.x;
  const int lane = tid & 63, wave = tid >> 6;
  const int wm = wave >> 1, wn = wave & 1;
  const int row0 = blockIdx.x * 128, n0 = blockIdx.y * 128;
  const int lr = lane & 15, ls = lane >> 4;

  f32x4 acc[4][4];
#pragma unroll
  for (int i = 0; i < 4; ++i)
#pragma unroll
    for (int j = 0; j < 4; ++j) acc[i][j] = (f32x4){0.f, 0.f, 0.f, 0.f};

  const int srow = tid >> 1, shalf = tid & 1;
  const float* Ap = A + (size_t)(row0 + srow) * lda + shalf * 16;
  const unsigned short* Bhp = Bh + (size_t)(n0 + srow) * Kpad + shalf * 16;
  const unsigned short* Blp = Bl + (size_t)(n0 + srow) * Kpad + shalf * 16;
  const int wo = srow * 32 + shalf * 16;
  const int aoff = (wm * 64 + lr) * 32 + ls * 8;
  const int boff = (wn * 64 + lr) * 32 + ls * 8;

  const int nk = Kpad >> 5;
  for (int kt = 0; kt < nk; ++kt) {
    const int kk = kt * 32 + shalf * 16;
    float av[16];
#pragma unroll
    for (int q = 0; q < 4; ++q) {
      float4 v;
      if (kk + q * 4 + 4 <= KsrcA) v = *(const float4*)(Ap + kt * 32 + q * 4);
      else v = make_float4(0.f, 0.f, 0.f, 0.f);
      av[q * 4 + 0] = v.x; av[q * 4 + 1] = v.y;
      av[q * 4 + 2] = v.z; av[q * 4 + 3] = v.w;
    }
    short8 h0, h1, l0, l1;
#pragma unroll
    for (int e = 0; e < 8; ++e) {
      unsigned short hh, ll;
      split2(av[e], hh, ll);     h0[e] = (short)hh; l0[e] = (short)ll;
      split2(av[8 + e], hh, ll); h1[e] = (short)hh; l1[e] = (short)ll;
    }
    short8 gb0 = *(const short8*)(Bhp + kt * 32);
    short8 gb1 = *(const short8*)(Bhp + kt * 32 + 8);
    short8 gc0 = *(const short8*)(Blp + kt * 32);
    short8 gc1 = *(const short8*)(Blp + kt * 32 + 8);
    *(short8*)&sAh[wo] = h0; *(short8*)&sAh[wo + 8] = h1;
    *(short8*)&sAl[wo] = l0; *(short8*)&sAl[wo + 8] = l1;
    *(short8*)&sBh[wo] = gb0; *(short8*)&sBh[wo + 8] = gb1;
    *(short8*)&sBl[wo] = gc0; *(short8*)&sBl[wo + 8] = gc1;
    __syncthreads();

    short8 fa[4], fb[4];
#pragma unroll
    for (int i = 0; i < 4; ++i) fa[i] = *(const short8*)&sAh[aoff + i * 512];
#pragma unroll
    for (int j = 0; j < 4; ++j) fb[j] = *(const short8*)&sBh[boff + j * 512];
#pragma unroll
    for (int i = 0; i < 4; ++i)
#pragma unroll
      for (int j = 0; j < 4; ++j)
        acc[i][j] = __builtin_amdgcn_mfma_f32_16x16x32_bf16(fa[i], fb[j], acc[i][j], 0, 0, 0);
    short8 fc[4];
#pragma unroll
    for (int j = 0; j < 4; ++j) fc[j] = *(const short8*)&sBl[boff + j * 512];
#pragma unroll
    for (int i = 0; i < 4; ++i)
#pragma unroll
      for (int j = 0; j < 4; ++j)
        acc[i][j] = __builtin_amdgcn_mfma_f32_16x16x32_bf16(fa[i], fc[j], acc[i][j], 0, 0, 0);
#pragma unroll
    for (int i = 0; i < 4; ++i) fa[i] = *(const short8*)&sAl[aoff + i * 512];
#pragma unroll
    for (int i = 0; i < 4; ++i)
#pragma unroll
      for (int j = 0; j < 4; ++j)
        acc[i][j] = __builtin_amdgcn_mfma_f32_16x16x32_bf16(fa[i], fb[j], acc[i][j], 0, 0, 0);
    __syncthreads();
  }

  // ---------------- fused epilogue ----------------
  const int colb = n0 + wn * 64 + lr;
  const int rowb = row0 + wm * 64 + ls * 4;
  const int pmine = lane & 3;
  const int woff = (MODE == 0) ? 0 : 200;
  float w12j[4], addj[4];
#pragma unroll
  for (int j = 0; j < 4; ++j) {
    const int col = colb + j * 16;
    w12j[j] = (col < 800) ? W12[pmine * 400 + woff + (col >> 2)] : 0.f;
    if (MODE == 1) addj[j] = (col < 800) ? addv[col] : 0.f;
  }
  const int slice = slice_base + blockIdx.y * 2 + wn;
#pragma unroll
  for (int i = 0; i < 4; ++i) {
#pragma unroll
    for (int r = 0; r < 4; ++r) {
      const int row = rowb + i * 16 + r;
      float sp = 0.f;
#pragma unroll
      for (int j = 0; j < 4; ++j) {
        const int col = colb + j * 16;
        float v = acc[i][j][r];
        if (MODE == 0) {
          const unsigned bidx = (unsigned)row / 1000u;
          v += addv[bidx * NPAD + col];
        } else {
          v += addj[j];
        }
        v = fmaxf(v, __shfl_xor(v, 1));
        v = fmaxf(v, __shfl_xor(v, 2));
        if (MODE == 0 && (lane & 3) == 0)
          Cout[(size_t)row * KB + (col >> 2)] = v;
        sp = fmaf(v, w12j[j], sp);
      }
      sp += __shfl_xor(sp, 4);
      sp += __shfl_xor(sp, 8);
      if (lr < 4)
        partial[((size_t)row * NSLICE + slice) * 4 + lr] = sp;
    }
  }
}

// ---------------------------------------------------------------- alpha-reduce + argmax + lse
__global__ __launch_bounds__(256) void k_reduce(const float* __restrict__ partial,
    const float* __restrict__ b12, const int* __restrict__ dmask,
    const int* __restrict__ span, int tag,
    int* __restrict__ idx_out, float* __restrict__ atgt_out) {
  int b = blockIdx.x, t = threadIdx.x;
  __shared__ float vals[MM];
  __shared__ float rv[256];
  __shared__ int ri[256];
  float4 bb = *(const float4*)b12;
  float bestv = -3.4e38f; int besti = 0x7fffffff;
  for (int m = t; m < MM; m += 256) {
    const float4* pr = (const float4*)(partial + ((size_t)(b * MM + m)) * (NSLICE * 4));
    float4 a4 = bb;
#pragma unroll
    for (int s = 0; s < NSLICE; ++s) {
      float4 p4 = pr[s];
      a4.x += p4.x; a4.y += p4.y; a4.z += p4.z; a4.w += p4.w;
    }
    float v = fmaxf(fmaxf(a4.x, a4.y), fmaxf(a4.z, a4.w));
    if (!dmask[b * MM + m]) v += NEGV;
    vals[m] = v;
    if (v > bestv || (v == bestv && m < besti)) { bestv = v; besti = m; }
  }
  rv[t] = bestv; ri[t] = besti; __syncthreads();
  for (int s = 128; s > 0; s >>= 1) {
    if (t < s) {
      float v2 = rv[t + s]; int i2 = ri[t + s];
      if (v2 > rv[t] || (v2 == rv[t] && i2 < ri[t])) { rv[t] = v2; ri[t] = i2; }
    }
    __syncthreads();
  }
  float vmax = rv[0]; int vidx = ri[0];
  __syncthreads();
  float se = 0.f;
  for (int m = t; m < MM; m += 256) se += expf(vals[m] - vmax);
  rv[t] = se; __syncthreads();
  for (int s = 128; s > 0; s >>= 1) { if (t < s) rv[t] += rv[t + s]; __syncthreads(); }
  if (t == 0) {
    int tgt = span[b * 2 + tag];
    atgt_out[b] = vals[tgt] - vmax - logf(rv[0]);
    idx_out[b] = vidx;
  }
}

// ---------------------------------------------------------------- state update + loss
__global__ __launch_bounds__(64) void k_update(const int* __restrict__ idx_buf,
    const float* __restrict__ atgt, int* __restrict__ st, int* __restrict__ mstate,
    float* __restrict__ pout, float* __restrict__ loss, int first) {
  int b = threadIdx.x;
  int idx = idx_buf[b];
  int sold = st[b], msold = mstate[b];
  int snew = first ? idx : (msold ? idx : 0);
  int msnew = first ? 1 : ((snew != (msold ? sold : 0)) ? 1 : 0);
  st[b] = snew; mstate[b] = msnew;
  if (msnew) pout[b] = (float)snew;
  float asum = atgt[b];
  float csum = (float)msnew;
  for (int off = 32; off > 0; off >>= 1) {
    asum += __shfl_down(asum, off);
    csum += __shfl_down(csum, off);
  }
  if (b == 0) loss[0] += (-asum / (float)BB) * csum / (float)(BB * TT);
}

// ---------------------------------------------------------------- launch
extern "C" void kernel_launch(void* const* d_in, const int* in_sizes, int n_in,
                              void* d_out, int out_size, void* d_ws, size_t ws_size,
                              hipStream_t stream) {
  const float* U     = (const float*)d_in[0];
  const int*   dmask = (const int*)d_in[1];
  const int*   span  = (const int*)d_in[2];
  const float* w_ih  = (const float*)d_in[3];
  const float* w_hh  = (const float*)d_in[4];
  const float* b_ih  = (const float*)d_in[5];
  const float* b_hh  = (const float*)d_in[6];
  const float* Wr[2]  = {(const float*)d_in[7],  (const float*)d_in[14]};
  const float* W1[2]  = {(const float*)d_in[8],  (const float*)d_in[15]};
  const float* b1[2]  = {(const float*)d_in[9],  (const float*)d_in[16]};
  const float* W2[2]  = {(const float*)d_in[10], (const float*)d_in[17]};
  const float* b2[2]  = {(const float*)d_in[11], (const float*)d_in[18]};
  const float* W12[2] = {(const float*)d_in[12], (const float*)d_in[19]};
  const float* b12[2] = {(const float*)d_in[13], (const float*)d_in[20]};
  float* out = (float*)d_out;

  size_t off = 0;
  char* base = (char*)d_ws;
  auto alloc = [&](size_t n) {
    void* p = base + off;
    off += (n + 255) & ~(size_t)255;
    return p;
  };
  float* m1      = (float*)alloc((size_t)ROWS * KB * 4);          // 57.3 MB
  float* partial = (float*)alloc((size_t)ROWS * NSLICE * 4 * 4);  // 28.7 MB
  float* rcorr   = (float*)alloc((size_t)BB * NPAD * 4);
  float* ue      = (float*)alloc((size_t)BB * 400 * 4);
  float* hbuf    = (float*)alloc((size_t)BB * H * 4);
  float* cbuf    = (float*)alloc((size_t)BB * H * 4);
  float* atgt    = (float*)alloc((size_t)BB * 4);
  int* st_s = (int*)alloc(BB * 4);
  int* st_e = (int*)alloc(BB * 4);
  int* msb  = (int*)alloc(BB * 4);
  int* meb  = (int*)alloc(BB * 4);
  int* idxb = (int*)alloc(BB * 4);
  unsigned short *W1h[2], *W1l[2], *W2h[2], *W2l[2];
  for (int g = 0; g < 2; ++g) {
    W1h[g] = (unsigned short*)alloc((size_t)NPAD * KA * 2);
    W1l[g] = (unsigned short*)alloc((size_t)NPAD * KA * 2);
    W2h[g] = (unsigned short*)alloc((size_t)NPAD * KB * 2);
    W2l[g] = (unsigned short*)alloc((size_t)NPAD * KB * 2);
  }

  k_init<<<BB, 256, 0, stream>>>(dmask, st_s, st_e, msb, meb, hbuf, cbuf, out);
  for (int g = 0; g < 2; ++g) {
    k_split<<<NPAD, 256, 0, stream>>>(W1[g], 600, 0, 400, 800, W1h[g], W1l[g], KA);
    k_split<<<NPAD, 256, 0, stream>>>(W2[g], 200, 0, 200, 800, W2h[g], W2l[g], KB);
  }

  dim3 gg(ROWS / 128, NPAD / 128);   // 500 x 7
  for (int t = 0; t < TT; ++t) {
    int first = (t == 0) ? 1 : 0;
    // ---- tag s ----
    k_lstm_r<<<BB, 1024, 0, stream>>>(U, st_s, st_e, hbuf, cbuf, w_ih, w_hh, b_ih, b_hh,
                                      Wr[0], W1[0], b1[0], rcorr, ue);
    k_mgemm<0><<<gg, 256, 0, stream>>>(U, 400, 400, W1h[0], W1l[0], KA,
                                       rcorr, m1, partial, W12[0], 0);
    k_mgemm<1><<<gg, 256, 0, stream>>>(m1, KB, KB, W2h[0], W2l[0], KB,
                                       b2[0], nullptr, partial, W12[0], 14);
    k_reduce<<<BB, 256, 0, stream>>>(partial, b12[0], dmask, span, 0, idxb, atgt);
    k_update<<<1, 64, 0, stream>>>(idxb, atgt, st_s, msb, out + 1, out, first);
    // ---- tag e ----
    k_re<<<BB, 1024, 0, stream>>>(U, st_s, ue, hbuf, Wr[1], W1[1], b1[1], rcorr);
    k_mgemm<0><<<gg, 256, 0, stream>>>(U, 400, 400, W1h[1], W1l[1], KA,
                                       rcorr, m1, partial, W12[1], 0);
    k_mgemm<1><<<gg, 256, 0, stream>>>(m1, KB, KB, W2h[1], W2l[1], KB,
                                       b2[1], nullptr, partial, W12[1], 14);
    k_reduce<<<BB, 256, 0, stream>>>(partial, b12[1], dmask, span, 1, idxb, atgt);
    k_update<<<1, 64, 0, stream>>>(idxb, atgt, st_e, meb, out + 1 + BB, out, first);
  }
}